// Round 3
// baseline (381.378 us; speedup 1.0000x reference)
//
#include <hip/hip_runtime.h>
#include <hip/hip_bf16.h>
#include <cstddef>

#define BATCH 4
#define CDIM 256
#define HW 4096
#define MCTX 1024
#define CTX 256
#define HEADS 8
#define DHEAD 64
#define INNER 512

typedef __attribute__((ext_vector_type(8))) short bf16x8;
typedef __attribute__((ext_vector_type(4))) float f32x4;

static __device__ __forceinline__ ushort f2bf(float f) {
  __hip_bfloat16 h = __float2bfloat16(f);
  return *reinterpret_cast<ushort*>(&h);
}

// ---------------------------------------------------------------------------
// LN over channels of x with layout transpose. x:[b,256,4096] -> xn:[b,4096,256]
// Emits fp32 (for residual) and bf16 (for Q GEMM).
// ---------------------------------------------------------------------------
__global__ __launch_bounds__(256) void ln_x_kernel(
    const float* __restrict__ x, const float* __restrict__ g,
    const float* __restrict__ bta, float* __restrict__ xn,
    ushort* __restrict__ xnbf) {
  const int blk = blockIdx.x;
  const int bi = blk / (HW / 32);
  const int n0 = (blk % (HW / 32)) * 32;
  __shared__ float xt[32][257];
  __shared__ float smu[32], srs[32];
  const int t = threadIdx.x;
  const int nl = t & 31;
  const int c0 = t >> 5;
  const float* xb = x + (size_t)bi * CDIM * HW;
  #pragma unroll
  for (int c = c0; c < CDIM; c += 8)
    xt[nl][c] = xb[(size_t)c * HW + n0 + nl];
  __syncthreads();
  const int col = t >> 3, j = t & 7;
  float s = 0.f, ss = 0.f;
  #pragma unroll
  for (int c = j; c < CDIM; c += 8) {
    float v = xt[col][c];
    s += v; ss += v * v;
  }
  #pragma unroll
  for (int off = 1; off < 8; off <<= 1) {
    s += __shfl_xor(s, off);
    ss += __shfl_xor(ss, off);
  }
  if (j == 0) {
    float mu = s * (1.f / CDIM);
    smu[col] = mu;
    srs[col] = rsqrtf(ss * (1.f / CDIM) - mu * mu + 1e-5f);
  }
  __syncthreads();
  const float gv = g[t], bvv = bta[t];
  float* xnb = xn + ((size_t)bi * HW + n0) * CDIM;
  ushort* xbb = xnbf + ((size_t)bi * HW + n0) * CDIM;
  #pragma unroll 4
  for (int n = 0; n < 32; ++n) {
    float val = (xt[n][t] - smu[n]) * srs[n] * gv + bvv;
    xnb[(size_t)n * CDIM + t] = val;
    xbb[(size_t)n * CDIM + t] = f2bf(val);
  }
}

// ---------------------------------------------------------------------------
// LN y rows -> bf16. 4 waves per block, one row each.
// ---------------------------------------------------------------------------
__global__ __launch_bounds__(256) void ln_y_kernel(
    const float* __restrict__ y, const float* __restrict__ g,
    const float* __restrict__ bta, ushort* __restrict__ ynbf) {
  const int row = blockIdx.x * 4 + (threadIdx.x >> 6);
  const int t = threadIdx.x & 63;
  float4 v = ((const float4*)(y + (size_t)row * CTX))[t];
  float s = v.x + v.y + v.z + v.w;
  float ss = v.x * v.x + v.y * v.y + v.z * v.z + v.w * v.w;
  #pragma unroll
  for (int off = 1; off < 64; off <<= 1) {
    s += __shfl_xor(s, off);
    ss += __shfl_xor(ss, off);
  }
  float mu = s * (1.f / CTX);
  float rs = rsqrtf(ss * (1.f / CTX) - mu * mu + 1e-5f);
  float4 gv = ((const float4*)g)[t];
  float4 b4 = ((const float4*)bta)[t];
  ushort4 ob;
  ob.x = f2bf((v.x - mu) * rs * gv.x + b4.x);
  ob.y = f2bf((v.y - mu) * rs * gv.y + b4.y);
  ob.z = f2bf((v.z - mu) * rs * gv.z + b4.z);
  ob.w = f2bf((v.w - mu) * rs * gv.w + b4.w);
  *(ushort4*)(ynbf + (size_t)row * CTX + t * 4) = ob;
}

// ---------------------------------------------------------------------------
// Weight prep: W [K][N] fp32 -> Wt [N][K] bf16 (64x64 LDS transpose tiles)
// wprep3: Wq/Wk/Wv (all 256x512) in one launch, blockIdx.z selects.
// ---------------------------------------------------------------------------
static __device__ __forceinline__ void wprep_body(
    const float* __restrict__ W, ushort* __restrict__ Wt, int K, int N) {
  __shared__ ushort T[64][65];
  const int k0 = blockIdx.y * 64, n0 = blockIdx.x * 64;
  const int t = threadIdx.x;
  #pragma unroll
  for (int rr = 0; rr < 4; ++rr) {
    int row = rr * 16 + (t >> 4);          // k
    int c = (t & 15) * 4;                  // n
    float4 wv = *(const float4*)(W + (size_t)(k0 + row) * N + n0 + c);
    T[row][c + 0] = f2bf(wv.x); T[row][c + 1] = f2bf(wv.y);
    T[row][c + 2] = f2bf(wv.z); T[row][c + 3] = f2bf(wv.w);
  }
  __syncthreads();
  #pragma unroll
  for (int rr = 0; rr < 4; ++rr) {
    int nrow = rr * 16 + (t >> 4);
    int kc = (t & 15) * 4;
    ushort4 o;
    o.x = T[kc + 0][nrow]; o.y = T[kc + 1][nrow];
    o.z = T[kc + 2][nrow]; o.w = T[kc + 3][nrow];
    *(ushort4*)(Wt + (size_t)(n0 + nrow) * K + k0 + kc) = o;
  }
}

__global__ __launch_bounds__(256) void wprep3_kernel(
    const float* __restrict__ W0, const float* __restrict__ W1,
    const float* __restrict__ W2, ushort* __restrict__ T0,
    ushort* __restrict__ T1, ushort* __restrict__ T2) {
  const int z = blockIdx.z;
  const float* W = (z == 0) ? W0 : (z == 1) ? W1 : W2;
  ushort* Wt = (z == 0) ? T0 : (z == 1) ? T1 : T2;
  wprep_body(W, Wt, 256, 512);
}

__global__ __launch_bounds__(256) void wprep_kernel(
    const float* __restrict__ W, ushort* __restrict__ Wt, int K, int N) {
  wprep_body(W, Wt, K, N);
}

// ---------------------------------------------------------------------------
// V transpose per head: vbf [b*m][512] -> vt [b*h][64 d][1024 m]
// ---------------------------------------------------------------------------
__global__ __launch_bounds__(256) void vtr_kernel(
    const ushort* __restrict__ v, ushort* __restrict__ vt) {
  const int bh = blockIdx.z, bi = bh >> 3, h = bh & 7;
  const int m0 = blockIdx.x * 64;
  __shared__ ushort T[64][65];
  const int t = threadIdx.x;
  #pragma unroll
  for (int rr = 0; rr < 4; ++rr) {
    int row = rr * 16 + (t >> 4);          // m local
    int c = (t & 15) * 4;                  // d
    ushort4 vv = *(const ushort4*)(v + (size_t)(bi * MCTX + m0 + row) * INNER + h * DHEAD + c);
    T[row][c + 0] = vv.x; T[row][c + 1] = vv.y;
    T[row][c + 2] = vv.z; T[row][c + 3] = vv.w;
  }
  __syncthreads();
  #pragma unroll
  for (int rr = 0; rr < 4; ++rr) {
    int drow = rr * 16 + (t >> 4);
    int mc = (t & 15) * 4;
    ushort4 o;
    o.x = T[mc + 0][drow]; o.y = T[mc + 1][drow];
    o.z = T[mc + 2][drow]; o.w = T[mc + 3][drow];
    *(ushort4*)(vt + (size_t)(bh * 64 + drow) * MCTX + m0 + mc) = o;
  }
}

// ---------------------------------------------------------------------------
// bf16 MFMA GEMM: C[M][N] = A[M][K] @ Bt[N][K]^T, 128x128 tile, BK=32,
// 4 waves (2x2), each wave 64x64 = 4x4 tiles of 16x16x32 mfma.
// ---------------------------------------------------------------------------
template <bool HAS_BIAS, bool F32_RES_OUT>
__global__ __launch_bounds__(256) void mfma_gemm(
    const ushort* __restrict__ A, const ushort* __restrict__ Bt,
    const float* __restrict__ bias, const float* __restrict__ res,
    void* __restrict__ Cout, int M, int N, int K, float scale) {
  __shared__ ushort As[128 * 40];   // padded stride 40 shorts (80B)
  __shared__ ushort Bs[128 * 40];
  const int t = threadIdx.x;
  const int l = t & 63, w = t >> 6;
  const int lq = l & 15, lg = l >> 4;
  const int wr = w >> 1, wc = w & 1;
  const int m0 = blockIdx.y * 128, n0 = blockIdx.x * 128;
  f32x4 acc[4][4];
  #pragma unroll
  for (int mt = 0; mt < 4; ++mt)
    #pragma unroll
    for (int nt = 0; nt < 4; ++nt)
      #pragma unroll
      for (int e = 0; e < 4; ++e) acc[mt][nt][e] = 0.f;
  const int r = t >> 2, ch = (t & 3) * 8;
  for (int k0 = 0; k0 < K; k0 += 32) {
    uint4 a0 = *(const uint4*)(A + (size_t)(m0 + r) * K + k0 + ch);
    uint4 a1 = *(const uint4*)(A + (size_t)(m0 + r + 64) * K + k0 + ch);
    uint4 b0 = *(const uint4*)(Bt + (size_t)(n0 + r) * K + k0 + ch);
    uint4 b1 = *(const uint4*)(Bt + (size_t)(n0 + r + 64) * K + k0 + ch);
    __syncthreads();
    *(uint4*)(&As[r * 40 + ch]) = a0;
    *(uint4*)(&As[(r + 64) * 40 + ch]) = a1;
    *(uint4*)(&Bs[r * 40 + ch]) = b0;
    *(uint4*)(&Bs[(r + 64) * 40 + ch]) = b1;
    __syncthreads();
    bf16x8 af[4], bfr[4];
    #pragma unroll
    for (int mt = 0; mt < 4; ++mt)
      af[mt] = *(const bf16x8*)(&As[(wr * 64 + mt * 16 + lq) * 40 + lg * 8]);
    #pragma unroll
    for (int nt = 0; nt < 4; ++nt)
      bfr[nt] = *(const bf16x8*)(&Bs[(wc * 64 + nt * 16 + lq) * 40 + lg * 8]);
    #pragma unroll
    for (int mt = 0; mt < 4; ++mt)
      #pragma unroll
      for (int nt = 0; nt < 4; ++nt)
        acc[mt][nt] = __builtin_amdgcn_mfma_f32_16x16x32_bf16(
            af[mt], bfr[nt], acc[mt][nt], 0, 0, 0);
  }
  #pragma unroll
  for (int nt = 0; nt < 4; ++nt) {
    const int colc = n0 + wc * 64 + nt * 16 + lq;
    const float bcol = HAS_BIAS ? bias[colc] : 0.f;
    #pragma unroll
    for (int mt = 0; mt < 4; ++mt) {
      #pragma unroll
      for (int i = 0; i < 4; ++i) {
        const size_t row = (size_t)(m0 + wr * 64 + mt * 16 + lg * 4 + i);
        float v = acc[mt][nt][i] * scale + bcol;
        if (F32_RES_OUT) {
          ((float*)Cout)[row * N + colc] = v + res[row * N + colc];
        } else {
          ((ushort*)Cout)[row * N + colc] = f2bf(v);
        }
      }
    }
  }
}

// ---------------------------------------------------------------------------
// Flash attention, bf16 MFMA. q:[b*n][512] (pre-scaled 0.125*log2e), k:[b*m][512],
// vt:[b*h][64][1024]. Block: (b,h) x 128 q-rows; 4 waves (256 thr) x 32 q-rows
// (2 groups of 16). Swapped QK^T: St = mfma(K, Q); softmax via shfl_xor(16/32),
// exp2 domain. Single-buffer K/V LDS (24 KiB total -> 6 blocks/CU, 24 waves);
// next tile prefetched to regs at loop top, written to LDS between barriers.
// ak/vb LDS fragments shared across both q-groups; Ps shared across groups
// (same-wave RAW, in-order DS). Defer-max (THR=8, log2 domain).
// All 64x64 bf16 LDS tiles XOR-swizzled: short_idx ^= (row&7)<<3.
// ---------------------------------------------------------------------------
__global__ __launch_bounds__(256, 6) void attn_mfma(
    const ushort* __restrict__ q, const ushort* __restrict__ k,
    const ushort* __restrict__ vt, ushort* __restrict__ ao) {
  const int bi = blockIdx.z, h = blockIdx.y;
  const int n0 = blockIdx.x * 128;
  __shared__ ushort Ks[64 * 64];
  __shared__ ushort Vs[64 * 64];
  __shared__ ushort Ps[4][16 * 64];
  const int t = threadIdx.x;
  const int l = t & 63, w = t >> 6;
  const int lq = l & 15, lg = l >> 4;

  // Q fragments (B operand: col=q-row-in-tile, k=d) direct from global.
  bf16x8 bq[2][2];
  #pragma unroll
  for (int g = 0; g < 2; ++g) {
    const size_t qrow = (size_t)(bi * HW + n0 + w * 32 + g * 16 + lq);
    #pragma unroll
    for (int ks = 0; ks < 2; ++ks)
      bq[g][ks] = *(const bf16x8*)(q + qrow * INNER + h * DHEAD + ks * 32 + lg * 8);
  }

  float m_run[2] = {-1e30f, -1e30f}, l_run[2] = {0.f, 0.f};
  f32x4 oacc[2][4];
  #pragma unroll
  for (int g = 0; g < 2; ++g)
    #pragma unroll
    for (int dt = 0; dt < 4; ++dt)
      #pragma unroll
      for (int e = 0; e < 4; ++e) oacc[g][dt][e] = 0.f;

  // staging: 64x64 bf16 tile = 512 uint4; 256 threads -> 2 uint4 each per tile
  const int rr0 = t >> 3, cc0 = (t & 7) * 8;          // idx = t
  const int rr1 = (t + 256) >> 3, cc1 = cc0;          // idx = t + 256
  const ushort* kbase = k + (size_t)bi * MCTX * INNER + h * DHEAD;
  const ushort* vbase = vt + (size_t)((bi * HEADS + h) * 64) * MCTX;
  const int sidx0 = (rr0 * 64 + cc0) ^ ((rr0 & 7) << 3);
  const int sidx1 = (rr1 * 64 + cc1) ^ ((rr1 & 7) << 3);

  {  // stage tile 0
    uint4 ka = *(const uint4*)(kbase + (size_t)rr0 * INNER + cc0);
    uint4 kb2 = *(const uint4*)(kbase + (size_t)rr1 * INNER + cc1);
    uint4 va = *(const uint4*)(vbase + (size_t)rr0 * MCTX + cc0);
    uint4 vb2 = *(const uint4*)(vbase + (size_t)rr1 * MCTX + cc1);
    *(uint4*)(&Ks[sidx0]) = ka;  *(uint4*)(&Ks[sidx1]) = kb2;
    *(uint4*)(&Vs[sidx0]) = va;  *(uint4*)(&Vs[sidx1]) = vb2;
  }
  __syncthreads();

  for (int m0 = 0; m0 < MCTX; m0 += 64) {
    const bool more = (m0 + 64) < MCTX;
    uint4 kp0{}, kp1{}, vp0{}, vp1{};
    if (more) {  // prefetch next tile; loads fly under this tile's compute
      const int mn = m0 + 64;
      kp0 = *(const uint4*)(kbase + (size_t)(mn + rr0) * INNER + cc0);
      kp1 = *(const uint4*)(kbase + (size_t)(mn + rr1) * INNER + cc1);
      vp0 = *(const uint4*)(vbase + (size_t)rr0 * MCTX + mn + cc0);
      vp1 = *(const uint4*)(vbase + (size_t)rr1 * MCTX + mn + cc1);
    }
    // scores both groups: St[key][q], ak shared across groups
    f32x4 sc[2][4];
    #pragma unroll
    for (int g = 0; g < 2; ++g)
      #pragma unroll
      for (int j = 0; j < 4; ++j)
        #pragma unroll
        for (int e = 0; e < 4; ++e) sc[g][j][e] = 0.f;
    __builtin_amdgcn_s_setprio(1);
    #pragma unroll
    for (int j = 0; j < 4; ++j) {
      #pragma unroll
      for (int ks = 0; ks < 2; ++ks) {
        const int krow = j * 16 + lq;
        bf16x8 ak = *(const bf16x8*)(
            &Ks[(krow * 64 + ks * 32 + lg * 8) ^ ((krow & 7) << 3)]);
        sc[0][j] = __builtin_amdgcn_mfma_f32_16x16x32_bf16(ak, bq[0][ks], sc[0][j], 0, 0, 0);
        sc[1][j] = __builtin_amdgcn_mfma_f32_16x16x32_bf16(ak, bq[1][ks], sc[1][j], 0, 0, 0);
      }
    }
    __builtin_amdgcn_s_setprio(0);
    // per-group online softmax (q-row = lq; lanes {lq,+16,+32,+48} share it)
    bf16x8 pa[2][2];
    #pragma unroll
    for (int g = 0; g < 2; ++g) {
      float mloc = -1e30f;
      #pragma unroll
      for (int j = 0; j < 4; ++j)
        #pragma unroll
        for (int e = 0; e < 4; ++e) mloc = fmaxf(mloc, sc[g][j][e]);
      mloc = fmaxf(mloc, __shfl_xor(mloc, 16));
      mloc = fmaxf(mloc, __shfl_xor(mloc, 32));
      // defer-max: only rescale when some q-row's max grew by > 8 (log2 units)
      if (!__all((int)(mloc - m_run[g] <= 8.f))) {
        const float mnew = fmaxf(m_run[g], mloc);
        const float corr = __builtin_amdgcn_exp2f(m_run[g] - mnew);
        l_run[g] *= corr;
        m_run[g] = mnew;
        #pragma unroll
        for (int i = 0; i < 4; ++i) {
          float ci = __shfl(corr, lg * 4 + i);
          #pragma unroll
          for (int dt = 0; dt < 4; ++dt) oacc[g][dt][i] *= ci;
        }
      }
      float psum = 0.f;
      #pragma unroll
      for (int j = 0; j < 4; ++j)
        #pragma unroll
        for (int e = 0; e < 4; ++e) {
          float p = __builtin_amdgcn_exp2f(sc[g][j][e] - m_run[g]);
          sc[g][j][e] = p; psum += p;
        }
      psum += __shfl_xor(psum, 16);
      psum += __shfl_xor(psum, 32);
      l_run[g] += psum;
      // write P[q=lq][key] (bf16, swizzled) — per-wave region; group g reuses
      // the same region (same-wave RAW -> in-order DS, compiler waits)
      #pragma unroll
      for (int j = 0; j < 4; ++j) {
        uint2 pk;
        pk.x = (uint)f2bf(sc[g][j][0]) | ((uint)f2bf(sc[g][j][1]) << 16);
        pk.y = (uint)f2bf(sc[g][j][2]) | ((uint)f2bf(sc[g][j][3]) << 16);
        *(uint2*)(&Ps[w][(lq * 64 + j * 16 + lg * 4) ^ ((lq & 7) << 3)]) = pk;
      }
      #pragma unroll
      for (int ks = 0; ks < 2; ++ks)
        pa[g][ks] = *(const bf16x8*)(
            &Ps[w][(lq * 64 + ks * 32 + lg * 8) ^ ((lq & 7) << 3)]);
    }
    // PV both groups: O[q][d] += P @ V; vb shared across groups
    __builtin_amdgcn_s_setprio(1);
    #pragma unroll
    for (int dt = 0; dt < 4; ++dt) {
      #pragma unroll
      for (int ks = 0; ks < 2; ++ks) {
        const int vrow = dt * 16 + lq;
        bf16x8 vb = *(const bf16x8*)(
            &Vs[(vrow * 64 + ks * 32 + lg * 8) ^ ((vrow & 7) << 3)]);
        oacc[0][dt] = __builtin_amdgcn_mfma_f32_16x16x32_bf16(pa[0][ks], vb, oacc[0][dt], 0, 0, 0);
        oacc[1][dt] = __builtin_amdgcn_mfma_f32_16x16x32_bf16(pa[1][ks], vb, oacc[1][dt], 0, 0, 0);
      }
    }
    __builtin_amdgcn_s_setprio(0);
    if (more) {
      __syncthreads();                      // all waves done reading Ks/Vs
      *(uint4*)(&Ks[sidx0]) = kp0;  *(uint4*)(&Ks[sidx1]) = kp1;
      *(uint4*)(&Vs[sidx0]) = vp0;  *(uint4*)(&Vs[sidx1]) = vp1;
      __syncthreads();                      // next tile visible
    }
  }
  #pragma unroll
  for (int g = 0; g < 2; ++g) {
    const float rl = 1.f / l_run[g];
    #pragma unroll
    for (int i = 0; i < 4; ++i) {
      float li = __shfl(rl, lg * 4 + i);
      const size_t row = (size_t)(bi * HW + n0 + w * 32 + g * 16 + lg * 4 + i);
      #pragma unroll
      for (int dt = 0; dt < 4; ++dt)
        ao[row * INNER + h * DHEAD + dt * 16 + lq] = f2bf(oacc[g][dt][i] * li);
    }
  }
}

// ---------------------------------------------------------------------------
extern "C" void kernel_launch(void* const* d_in, const int* in_sizes, int n_in,
                              void* d_out, int out_size, void* d_ws, size_t ws_size,
                              hipStream_t stream) {
  const float* x     = (const float*)d_in[0];
  const float* y     = (const float*)d_in[1];
  const float* ln_xg = (const float*)d_in[2];
  const float* ln_xb = (const float*)d_in[3];
  const float* ln_yg = (const float*)d_in[4];
  const float* ln_yb = (const float*)d_in[5];
  const float* Wq    = (const float*)d_in[6];
  const float* Wk    = (const float*)d_in[7];
  const float* Wv    = (const float*)d_in[8];
  const float* bv    = (const float*)d_in[9];
  const float* Wo    = (const float*)d_in[10];
  const float* bo    = (const float*)d_in[11];
  float* out = (float*)d_out;

  char* p = (char*)d_ws;
  float*  xn   = (float*)p;  p += (size_t)16384 * 256 * 4;
  ushort* xnbf = (ushort*)p; p += (size_t)16384 * 256 * 2;
  ushort* ynbf = (ushort*)p; p += (size_t)4096 * 256 * 2;
  ushort* wtq  = (ushort*)p; p += (size_t)512 * 256 * 2;
  ushort* wtk  = (ushort*)p; p += (size_t)512 * 256 * 2;
  ushort* wtv  = (ushort*)p; p += (size_t)512 * 256 * 2;
  ushort* wto  = (ushort*)p; p += (size_t)256 * 512 * 2;
  ushort* qbf  = (ushort*)p; p += (size_t)16384 * 512 * 2;
  ushort* kbf  = (ushort*)p; p += (size_t)4096 * 512 * 2;
  ushort* vbf  = (ushort*)p; p += (size_t)4096 * 512 * 2;
  ushort* vtb  = (ushort*)p; p += (size_t)4096 * 512 * 2;
  ushort* aobf = (ushort*)p; p += (size_t)16384 * 512 * 2;

  wprep3_kernel<<<dim3(8, 4, 3), 256, 0, stream>>>(Wq, Wk, Wv, wtq, wtk, wtv);
  wprep_kernel<<<dim3(4, 8), 256, 0, stream>>>(Wo, wto, 512, 256);
  ln_x_kernel<<<dim3(BATCH * (HW / 32)), 256, 0, stream>>>(x, ln_xg, ln_xb, xn, xnbf);
  ln_y_kernel<<<dim3(BATCH * MCTX / 4), 256, 0, stream>>>(y, ln_yg, ln_yb, ynbf);
  // q = (xn @ Wq) * 0.125 * log2(e)  (scale folded; softmax runs in exp2 domain)
  mfma_gemm<false, false><<<dim3(4, 128), 256, 0, stream>>>(
      xnbf, wtq, nullptr, nullptr, qbf, 16384, 512, 256, 0.1803368801111204f);
  mfma_gemm<false, false><<<dim3(4, 32), 256, 0, stream>>>(
      ynbf, wtk, nullptr, nullptr, kbf, 4096, 512, 256, 1.f);
  mfma_gemm<true, false><<<dim3(4, 32), 256, 0, stream>>>(
      ynbf, wtv, bv, nullptr, vbf, 4096, 512, 256, 1.f);
  vtr_kernel<<<dim3(16, 1, 32), 256, 0, stream>>>(vbf, vtb);
  attn_mfma<<<dim3(HW / 128, HEADS, BATCH), 256, 0, stream>>>(qbf, kbf, vtb, aobf);
  // out = ao @ Wo + bo + xn
  mfma_gemm<true, true><<<dim3(2, 128), 256, 0, stream>>>(
      aobf, wto, bo, xn, out, 16384, 256, 512, 1.f);
}

// Round 4
// 124.749 us; speedup vs baseline: 3.0572x; 3.0572x over previous
//
#include <hip/hip_runtime.h>
#include <hip/hip_bf16.h>
#include <cstddef>

#define BATCH 4
#define CDIM 256
#define HW 4096
#define MCTX 1024
#define CTX 256
#define HEADS 8
#define DHEAD 64
#define INNER 512

typedef __attribute__((ext_vector_type(8))) short bf16x8;
typedef __attribute__((ext_vector_type(4))) float f32x4;

static __device__ __forceinline__ ushort f2bf(float f) {
  __hip_bfloat16 h = __float2bfloat16(f);
  return *reinterpret_cast<ushort*>(&h);
}

// ---------------------------------------------------------------------------
// LN over channels of x with layout transpose. x:[b,256,4096] -> xn:[b,4096,256]
// Emits fp32 (for residual) and bf16 (for Q GEMM).
// ---------------------------------------------------------------------------
__global__ __launch_bounds__(256) void ln_x_kernel(
    const float* __restrict__ x, const float* __restrict__ g,
    const float* __restrict__ bta, float* __restrict__ xn,
    ushort* __restrict__ xnbf) {
  const int blk = blockIdx.x;
  const int bi = blk / (HW / 32);
  const int n0 = (blk % (HW / 32)) * 32;
  __shared__ float xt[32][257];
  __shared__ float smu[32], srs[32];
  const int t = threadIdx.x;
  const int nl = t & 31;
  const int c0 = t >> 5;
  const float* xb = x + (size_t)bi * CDIM * HW;
  #pragma unroll
  for (int c = c0; c < CDIM; c += 8)
    xt[nl][c] = xb[(size_t)c * HW + n0 + nl];
  __syncthreads();
  const int col = t >> 3, j = t & 7;
  float s = 0.f, ss = 0.f;
  #pragma unroll
  for (int c = j; c < CDIM; c += 8) {
    float v = xt[col][c];
    s += v; ss += v * v;
  }
  #pragma unroll
  for (int off = 1; off < 8; off <<= 1) {
    s += __shfl_xor(s, off);
    ss += __shfl_xor(ss, off);
  }
  if (j == 0) {
    float mu = s * (1.f / CDIM);
    smu[col] = mu;
    srs[col] = rsqrtf(ss * (1.f / CDIM) - mu * mu + 1e-5f);
  }
  __syncthreads();
  const float gv = g[t], bvv = bta[t];
  float* xnb = xn + ((size_t)bi * HW + n0) * CDIM;
  ushort* xbb = xnbf + ((size_t)bi * HW + n0) * CDIM;
  #pragma unroll 4
  for (int n = 0; n < 32; ++n) {
    float val = (xt[n][t] - smu[n]) * srs[n] * gv + bvv;
    xnb[(size_t)n * CDIM + t] = val;
    xbb[(size_t)n * CDIM + t] = f2bf(val);
  }
}

// ---------------------------------------------------------------------------
// LN y rows -> bf16. 4 waves per block, one row each.
// ---------------------------------------------------------------------------
__global__ __launch_bounds__(256) void ln_y_kernel(
    const float* __restrict__ y, const float* __restrict__ g,
    const float* __restrict__ bta, ushort* __restrict__ ynbf) {
  const int row = blockIdx.x * 4 + (threadIdx.x >> 6);
  const int t = threadIdx.x & 63;
  float4 v = ((const float4*)(y + (size_t)row * CTX))[t];
  float s = v.x + v.y + v.z + v.w;
  float ss = v.x * v.x + v.y * v.y + v.z * v.z + v.w * v.w;
  #pragma unroll
  for (int off = 1; off < 64; off <<= 1) {
    s += __shfl_xor(s, off);
    ss += __shfl_xor(ss, off);
  }
  float mu = s * (1.f / CTX);
  float rs = rsqrtf(ss * (1.f / CTX) - mu * mu + 1e-5f);
  float4 gv = ((const float4*)g)[t];
  float4 b4 = ((const float4*)bta)[t];
  ushort4 ob;
  ob.x = f2bf((v.x - mu) * rs * gv.x + b4.x);
  ob.y = f2bf((v.y - mu) * rs * gv.y + b4.y);
  ob.z = f2bf((v.z - mu) * rs * gv.z + b4.z);
  ob.w = f2bf((v.w - mu) * rs * gv.w + b4.w);
  *(ushort4*)(ynbf + (size_t)row * CTX + t * 4) = ob;
}

// ---------------------------------------------------------------------------
// Weight prep: W [K][N] fp32 -> Wt [N][K] bf16 (64x64 LDS transpose tiles)
// wprep3: Wq/Wk/Wv (all 256x512) in one launch, blockIdx.z selects.
// ---------------------------------------------------------------------------
static __device__ __forceinline__ void wprep_body(
    const float* __restrict__ W, ushort* __restrict__ Wt, int K, int N) {
  __shared__ ushort T[64][65];
  const int k0 = blockIdx.y * 64, n0 = blockIdx.x * 64;
  const int t = threadIdx.x;
  #pragma unroll
  for (int rr = 0; rr < 4; ++rr) {
    int row = rr * 16 + (t >> 4);          // k
    int c = (t & 15) * 4;                  // n
    float4 wv = *(const float4*)(W + (size_t)(k0 + row) * N + n0 + c);
    T[row][c + 0] = f2bf(wv.x); T[row][c + 1] = f2bf(wv.y);
    T[row][c + 2] = f2bf(wv.z); T[row][c + 3] = f2bf(wv.w);
  }
  __syncthreads();
  #pragma unroll
  for (int rr = 0; rr < 4; ++rr) {
    int nrow = rr * 16 + (t >> 4);
    int kc = (t & 15) * 4;
    ushort4 o;
    o.x = T[kc + 0][nrow]; o.y = T[kc + 1][nrow];
    o.z = T[kc + 2][nrow]; o.w = T[kc + 3][nrow];
    *(ushort4*)(Wt + (size_t)(n0 + nrow) * K + k0 + kc) = o;
  }
}

__global__ __launch_bounds__(256) void wprep3_kernel(
    const float* __restrict__ W0, const float* __restrict__ W1,
    const float* __restrict__ W2, ushort* __restrict__ T0,
    ushort* __restrict__ T1, ushort* __restrict__ T2) {
  const int z = blockIdx.z;
  const float* W = (z == 0) ? W0 : (z == 1) ? W1 : W2;
  ushort* Wt = (z == 0) ? T0 : (z == 1) ? T1 : T2;
  wprep_body(W, Wt, 256, 512);
}

__global__ __launch_bounds__(256) void wprep_kernel(
    const float* __restrict__ W, ushort* __restrict__ Wt, int K, int N) {
  wprep_body(W, Wt, K, N);
}

// ---------------------------------------------------------------------------
// V transpose per head: vbf [b*m][512] -> vt [b*h][64 d][1024 m]
// ---------------------------------------------------------------------------
__global__ __launch_bounds__(256) void vtr_kernel(
    const ushort* __restrict__ v, ushort* __restrict__ vt) {
  const int bh = blockIdx.z, bi = bh >> 3, h = bh & 7;
  const int m0 = blockIdx.x * 64;
  __shared__ ushort T[64][65];
  const int t = threadIdx.x;
  #pragma unroll
  for (int rr = 0; rr < 4; ++rr) {
    int row = rr * 16 + (t >> 4);          // m local
    int c = (t & 15) * 4;                  // d
    ushort4 vv = *(const ushort4*)(v + (size_t)(bi * MCTX + m0 + row) * INNER + h * DHEAD + c);
    T[row][c + 0] = vv.x; T[row][c + 1] = vv.y;
    T[row][c + 2] = vv.z; T[row][c + 3] = vv.w;
  }
  __syncthreads();
  #pragma unroll
  for (int rr = 0; rr < 4; ++rr) {
    int drow = rr * 16 + (t >> 4);
    int mc = (t & 15) * 4;
    ushort4 o;
    o.x = T[mc + 0][drow]; o.y = T[mc + 1][drow];
    o.z = T[mc + 2][drow]; o.w = T[mc + 3][drow];
    *(ushort4*)(vt + (size_t)(bh * 64 + drow) * MCTX + m0 + mc) = o;
  }
}

// ---------------------------------------------------------------------------
// bf16 MFMA GEMM: C[M][N] = A[M][K] @ Bt[N][K]^T, 128x128 tile, BK=32,
// 4 waves (2x2), each wave 64x64 = 4x4 tiles of 16x16x32 mfma.
// ---------------------------------------------------------------------------
template <bool HAS_BIAS, bool F32_RES_OUT>
__global__ __launch_bounds__(256) void mfma_gemm(
    const ushort* __restrict__ A, const ushort* __restrict__ Bt,
    const float* __restrict__ bias, const float* __restrict__ res,
    void* __restrict__ Cout, int M, int N, int K, float scale) {
  __shared__ ushort As[128 * 40];   // padded stride 40 shorts (80B)
  __shared__ ushort Bs[128 * 40];
  const int t = threadIdx.x;
  const int l = t & 63, w = t >> 6;
  const int lq = l & 15, lg = l >> 4;
  const int wr = w >> 1, wc = w & 1;
  const int m0 = blockIdx.y * 128, n0 = blockIdx.x * 128;
  f32x4 acc[4][4];
  #pragma unroll
  for (int mt = 0; mt < 4; ++mt)
    #pragma unroll
    for (int nt = 0; nt < 4; ++nt)
      #pragma unroll
      for (int e = 0; e < 4; ++e) acc[mt][nt][e] = 0.f;
  const int r = t >> 2, ch = (t & 3) * 8;
  for (int k0 = 0; k0 < K; k0 += 32) {
    uint4 a0 = *(const uint4*)(A + (size_t)(m0 + r) * K + k0 + ch);
    uint4 a1 = *(const uint4*)(A + (size_t)(m0 + r + 64) * K + k0 + ch);
    uint4 b0 = *(const uint4*)(Bt + (size_t)(n0 + r) * K + k0 + ch);
    uint4 b1 = *(const uint4*)(Bt + (size_t)(n0 + r + 64) * K + k0 + ch);
    __syncthreads();
    *(uint4*)(&As[r * 40 + ch]) = a0;
    *(uint4*)(&As[(r + 64) * 40 + ch]) = a1;
    *(uint4*)(&Bs[r * 40 + ch]) = b0;
    *(uint4*)(&Bs[(r + 64) * 40 + ch]) = b1;
    __syncthreads();
    bf16x8 af[4], bfr[4];
    #pragma unroll
    for (int mt = 0; mt < 4; ++mt)
      af[mt] = *(const bf16x8*)(&As[(wr * 64 + mt * 16 + lq) * 40 + lg * 8]);
    #pragma unroll
    for (int nt = 0; nt < 4; ++nt)
      bfr[nt] = *(const bf16x8*)(&Bs[(wc * 64 + nt * 16 + lq) * 40 + lg * 8]);
    #pragma unroll
    for (int mt = 0; mt < 4; ++mt)
      #pragma unroll
      for (int nt = 0; nt < 4; ++nt)
        acc[mt][nt] = __builtin_amdgcn_mfma_f32_16x16x32_bf16(
            af[mt], bfr[nt], acc[mt][nt], 0, 0, 0);
  }
  #pragma unroll
  for (int nt = 0; nt < 4; ++nt) {
    const int colc = n0 + wc * 64 + nt * 16 + lq;
    const float bcol = HAS_BIAS ? bias[colc] : 0.f;
    #pragma unroll
    for (int mt = 0; mt < 4; ++mt) {
      #pragma unroll
      for (int i = 0; i < 4; ++i) {
        const size_t row = (size_t)(m0 + wr * 64 + mt * 16 + lg * 4 + i);
        float v = acc[mt][nt][i] * scale + bcol;
        if (F32_RES_OUT) {
          ((float*)Cout)[row * N + colc] = v + res[row * N + colc];
        } else {
          ((ushort*)Cout)[row * N + colc] = f2bf(v);
        }
      }
    }
  }
}

// ---------------------------------------------------------------------------
// Flash attention, bf16 MFMA. q:[b*n][512] (pre-scaled 0.125*log2e), k:[b*m][512],
// vt:[b*h][64][1024]. Block: (b,h) x 256 q-rows; 8 waves x 32 q-rows (2 groups
// of 16) at 512 threads. Swapped QK^T: St = mfma(K, Q); softmax via
// shfl_xor(16/32), exp2 domain. K/V LDS double-buffered -> ONE barrier per
// tile; next tile prefetched to regs at loop top (latency under compute).
// Reorder: sm(g0) -> writeP0 -> stageKV(buf^1) -> sm(g1) -> writeP1 -> read
// pa -> PV: group-1 softmax hides group-0's Ps write->read LDS latency, and
// stage writes drain during sm1+PV instead of stalling before the barrier.
// XCD swizzle: 512 blocks, swz=(bid&7)*64+(bid>>3) -> each XCD owns 4 (bi,h)
// K/V streams (1 MB, L2-resident) shared by its 16 q-blocks.
// Defer-max (THR=8, log2 domain) skips O-rescale on most tiles.
// All 64x64 bf16 LDS tiles XOR-swizzled: short_idx ^= (row&7)<<3.
// NOTE: needs ~128 VGPR; do NOT raise min-waves past 4/EU (r3: forced spill,
// 660 MB scratch traffic, 5x regression).
// ---------------------------------------------------------------------------
__global__ __launch_bounds__(512, 4) void attn_mfma(
    const ushort* __restrict__ q, const ushort* __restrict__ k,
    const ushort* __restrict__ vt, ushort* __restrict__ ao) {
  // XCD-aware swizzle (bijective: 512 = 8 * 64)
  const int bid = blockIdx.x + 16 * (blockIdx.y + 8 * blockIdx.z);
  const int swz = (bid & 7) * 64 + (bid >> 3);
  const int bi = swz >> 7;
  const int h = (swz >> 4) & 7;
  const int n0 = (swz & 15) * 256;
  __shared__ ushort Ks[2][64 * 64];
  __shared__ ushort Vs[2][64 * 64];
  __shared__ ushort Ps[8][2][16 * 64];
  const int t = threadIdx.x;
  const int l = t & 63, w = t >> 6;
  const int lq = l & 15, lg = l >> 4;

  // Q fragments (B operand: col=q-row-in-tile, k=d) direct from global.
  bf16x8 bq[2][2];
  #pragma unroll
  for (int g = 0; g < 2; ++g) {
    const size_t qrow = (size_t)(bi * HW + n0 + w * 32 + g * 16 + lq);
    #pragma unroll
    for (int ks = 0; ks < 2; ++ks)
      bq[g][ks] = *(const bf16x8*)(q + qrow * INNER + h * DHEAD + ks * 32 + lg * 8);
  }

  float m_run[2] = {-1e30f, -1e30f}, l_run[2] = {0.f, 0.f};
  f32x4 oacc[2][4];
  #pragma unroll
  for (int g = 0; g < 2; ++g)
    #pragma unroll
    for (int dt = 0; dt < 4; ++dt)
      #pragma unroll
      for (int e = 0; e < 4; ++e) oacc[g][dt][e] = 0.f;

  // staging: 64x64 bf16 tile = 512 uint4; 512 threads -> 1 uint4 each per tile
  const int rr = t >> 3, cc = (t & 7) * 8;
  const ushort* kptr = k + (size_t)(bi * MCTX + rr) * INNER + h * DHEAD + cc;
  const ushort* vptr = vt + (size_t)((bi * HEADS + h) * 64 + rr) * MCTX + cc;
  const int sidx = (rr * 64 + cc) ^ ((rr & 7) << 3);

  {  // stage tile 0 into buffer 0
    uint4 k0v = *(const uint4*)(kptr);
    uint4 v0v = *(const uint4*)(vptr);
    *(uint4*)(&Ks[0][sidx]) = k0v;
    *(uint4*)(&Vs[0][sidx]) = v0v;
  }
  __syncthreads();

  // softmax for one q-group: consumes scg (scores -> P), updates running
  // max/sum and rescales oa; writes bf16 P to psw (per-wave LDS region).
  // All inlined with compile-time-constant call sites (no runtime indexing).
  auto softmax_group = [&](f32x4 (&scg)[4], float& mr, float& lr,
                           f32x4 (&oa)[4], ushort* psw) {
    float mloc = -1e30f;
    #pragma unroll
    for (int j = 0; j < 4; ++j)
      #pragma unroll
      for (int e = 0; e < 4; ++e) mloc = fmaxf(mloc, scg[j][e]);
    mloc = fmaxf(mloc, __shfl_xor(mloc, 16));
    mloc = fmaxf(mloc, __shfl_xor(mloc, 32));
    // defer-max: only rescale when some q-row's max grew by > 8 (log2 units)
    if (!__all((int)(mloc - mr <= 8.f))) {
      const float mnew = fmaxf(mr, mloc);
      const float corr = __builtin_amdgcn_exp2f(mr - mnew);
      lr *= corr;
      mr = mnew;
      #pragma unroll
      for (int i = 0; i < 4; ++i) {
        float ci = __shfl(corr, lg * 4 + i);
        #pragma unroll
        for (int dt = 0; dt < 4; ++dt) oa[dt][i] *= ci;
      }
    }
    float psum = 0.f;
    #pragma unroll
    for (int j = 0; j < 4; ++j)
      #pragma unroll
      for (int e = 0; e < 4; ++e) {
        float p = __builtin_amdgcn_exp2f(scg[j][e] - mr);
        scg[j][e] = p; psum += p;
      }
    psum += __shfl_xor(psum, 16);
    psum += __shfl_xor(psum, 32);
    lr += psum;
    // write P[q=lq][key] (bf16, swizzled) — per-wave region, no barrier
    #pragma unroll
    for (int j = 0; j < 4; ++j) {
      uint2 pk;
      pk.x = (uint)f2bf(scg[j][0]) | ((uint)f2bf(scg[j][1]) << 16);
      pk.y = (uint)f2bf(scg[j][2]) | ((uint)f2bf(scg[j][3]) << 16);
      *(uint2*)(psw + ((lq * 64 + j * 16 + lg * 4) ^ ((lq & 7) << 3))) = pk;
    }
  };

  #pragma unroll 2
  for (int m0 = 0; m0 < MCTX; m0 += 64) {
    const int buf = (m0 >> 6) & 1;
    const bool more = (m0 + 64) < MCTX;
    uint4 kpre{}, vpre{};
    if (more) {  // prefetch next tile; consumed mid-iteration, after sm(g0)
      kpre = *(const uint4*)(kptr + (size_t)(m0 + 64) * INNER);
      vpre = *(const uint4*)(vptr + (m0 + 64));
    }
    // scores both groups: St[key][q], ak shared across groups
    f32x4 sc[2][4];
    #pragma unroll
    for (int g = 0; g < 2; ++g)
      #pragma unroll
      for (int j = 0; j < 4; ++j)
        #pragma unroll
        for (int e = 0; e < 4; ++e) sc[g][j][e] = 0.f;
    __builtin_amdgcn_s_setprio(1);
    #pragma unroll
    for (int j = 0; j < 4; ++j) {
      #pragma unroll
      for (int ks = 0; ks < 2; ++ks) {
        const int krow = j * 16 + lq;
        bf16x8 ak = *(const bf16x8*)(
            &Ks[buf][(krow * 64 + ks * 32 + lg * 8) ^ ((krow & 7) << 3)]);
        sc[0][j] = __builtin_amdgcn_mfma_f32_16x16x32_bf16(ak, bq[0][ks], sc[0][j], 0, 0, 0);
        sc[1][j] = __builtin_amdgcn_mfma_f32_16x16x32_bf16(ak, bq[1][ks], sc[1][j], 0, 0, 0);
      }
    }
    __builtin_amdgcn_s_setprio(0);
    // group 0 softmax + P write
    softmax_group(sc[0], m_run[0], l_run[0], oacc[0], &Ps[w][0][0]);
    // stage next tile into the other buffer (safe: buf^1 last read before
    // the previous barrier); drains during sm(g1) + PV
    if (more) {
      *(uint4*)(&Ks[buf ^ 1][sidx]) = kpre;
      *(uint4*)(&Vs[buf ^ 1][sidx]) = vpre;
    }
    // group 1 softmax + P write (hides group-0 Ps write->read latency)
    softmax_group(sc[1], m_run[1], l_run[1], oacc[1], &Ps[w][1][0]);
    // read P fragments for both groups
    bf16x8 pa[2][2];
    #pragma unroll
    for (int g = 0; g < 2; ++g)
      #pragma unroll
      for (int ks = 0; ks < 2; ++ks)
        pa[g][ks] = *(const bf16x8*)(
            &Ps[w][g][(lq * 64 + ks * 32 + lg * 8) ^ ((lq & 7) << 3)]);
    // PV both groups: O[q][d] += P @ V; vb shared across groups
    __builtin_amdgcn_s_setprio(1);
    #pragma unroll
    for (int dt = 0; dt < 4; ++dt) {
      #pragma unroll
      for (int ks = 0; ks < 2; ++ks) {
        const int vrow = dt * 16 + lq;
        bf16x8 vb = *(const bf16x8*)(
            &Vs[buf][(vrow * 64 + ks * 32 + lg * 8) ^ ((vrow & 7) << 3)]);
        oacc[0][dt] = __builtin_amdgcn_mfma_f32_16x16x32_bf16(pa[0][ks], vb, oacc[0][dt], 0, 0, 0);
        oacc[1][dt] = __builtin_amdgcn_mfma_f32_16x16x32_bf16(pa[1][ks], vb, oacc[1][dt], 0, 0, 0);
      }
    }
    __builtin_amdgcn_s_setprio(0);
    __syncthreads();
  }
  #pragma unroll
  for (int g = 0; g < 2; ++g) {
    const float rl = 1.f / l_run[g];
    #pragma unroll
    for (int i = 0; i < 4; ++i) {
      float li = __shfl(rl, lg * 4 + i);
      const size_t row = (size_t)(bi * HW + n0 + w * 32 + g * 16 + lg * 4 + i);
      #pragma unroll
      for (int dt = 0; dt < 4; ++dt)
        ao[row * INNER + h * DHEAD + dt * 16 + lq] = f2bf(oacc[g][dt][i] * li);
    }
  }
}

// ---------------------------------------------------------------------------
extern "C" void kernel_launch(void* const* d_in, const int* in_sizes, int n_in,
                              void* d_out, int out_size, void* d_ws, size_t ws_size,
                              hipStream_t stream) {
  const float* x     = (const float*)d_in[0];
  const float* y     = (const float*)d_in[1];
  const float* ln_xg = (const float*)d_in[2];
  const float* ln_xb = (const float*)d_in[3];
  const float* ln_yg = (const float*)d_in[4];
  const float* ln_yb = (const float*)d_in[5];
  const float* Wq    = (const float*)d_in[6];
  const float* Wk    = (const float*)d_in[7];
  const float* Wv    = (const float*)d_in[8];
  const float* bv    = (const float*)d_in[9];
  const float* Wo    = (const float*)d_in[10];
  const float* bo    = (const float*)d_in[11];
  float* out = (float*)d_out;

  char* p = (char*)d_ws;
  float*  xn   = (float*)p;  p += (size_t)16384 * 256 * 4;
  ushort* xnbf = (ushort*)p; p += (size_t)16384 * 256 * 2;
  ushort* ynbf = (ushort*)p; p += (size_t)4096 * 256 * 2;
  ushort* wtq  = (ushort*)p; p += (size_t)512 * 256 * 2;
  ushort* wtk  = (ushort*)p; p += (size_t)512 * 256 * 2;
  ushort* wtv  = (ushort*)p; p += (size_t)512 * 256 * 2;
  ushort* wto  = (ushort*)p; p += (size_t)256 * 512 * 2;
  ushort* qbf  = (ushort*)p; p += (size_t)16384 * 512 * 2;
  ushort* kbf  = (ushort*)p; p += (size_t)4096 * 512 * 2;
  ushort* vbf  = (ushort*)p; p += (size_t)4096 * 512 * 2;
  ushort* vtb  = (ushort*)p; p += (size_t)4096 * 512 * 2;
  ushort* aobf = (ushort*)p; p += (size_t)16384 * 512 * 2;

  wprep3_kernel<<<dim3(8, 4, 3), 256, 0, stream>>>(Wq, Wk, Wv, wtq, wtk, wtv);
  wprep_kernel<<<dim3(4, 8), 256, 0, stream>>>(Wo, wto, 512, 256);
  ln_x_kernel<<<dim3(BATCH * (HW / 32)), 256, 0, stream>>>(x, ln_xg, ln_xb, xn, xnbf);
  ln_y_kernel<<<dim3(BATCH * MCTX / 4), 256, 0, stream>>>(y, ln_yg, ln_yb, ynbf);
  // q = (xn @ Wq) * 0.125 * log2(e)  (scale folded; softmax runs in exp2 domain)
  mfma_gemm<false, false><<<dim3(4, 128), 256, 0, stream>>>(
      xnbf, wtq, nullptr, nullptr, qbf, 16384, 512, 256, 0.1803368801111204f);
  mfma_gemm<false, false><<<dim3(4, 32), 256, 0, stream>>>(
      ynbf, wtk, nullptr, nullptr, kbf, 4096, 512, 256, 1.f);
  mfma_gemm<true, false><<<dim3(4, 32), 256, 0, stream>>>(
      ynbf, wtv, bv, nullptr, vbf, 4096, 512, 256, 1.f);
  vtr_kernel<<<dim3(16, 1, 32), 256, 0, stream>>>(vbf, vtb);
  attn_mfma<<<dim3(HW / 256, HEADS, BATCH), 512, 0, stream>>>(qbf, kbf, vtb, aobf);
  // out = ao @ Wo + bo + xn
  mfma_gemm<true, true><<<dim3(2, 128), 256, 0, stream>>>(
      aobf, wto, bo, xn, out, 16384, 256, 512, 1.f);
}